// Round 22
// baseline (568.614 us; speedup 1.0000x reference)
//
#include <hip/hip_runtime.h>
#include <hip/hip_bf16.h>

// Geo2Vec fused MLP. Round 22: 32x32x16 MFMA on the R16 base.
// -18% matrix-pipe cycles (m119: 8.07cy/32k FLOP vs 4.85cy/16k) and half the
// MFMA issue slots. Wave = 64rows x 32cols = two 32x32 tiles; K-parallel acc
// pairs (dep distance 4); B 4-deep, A 2-deep; 4 swizzle bases per region
// (colbyte stride is 32B); natural-order B pack; b16 epilogue stores.

typedef __attribute__((ext_vector_type(8))) __bf16 bfv8;
typedef __attribute__((ext_vector_type(8))) short s16x8;
typedef __attribute__((ext_vector_type(16))) float f32x16;
typedef __attribute__((ext_vector_type(4))) int i32x4;

__device__ __forceinline__ short f2bf(float f) {
  unsigned u = __builtin_bit_cast(unsigned, f);
  u = (u + 0x7fffu + ((u >> 16) & 1u)) >> 16;
  return (short)u;
}
__device__ __forceinline__ float bf2f(short s) {
  unsigned u = ((unsigned)(unsigned short)s) << 16;
  return __builtin_bit_cast(float, u);
}
__device__ __forceinline__ int swzaddr(int base, int stride, int row, int colbyte) {
  return base + row * stride + (colbyte ^ (((row & 7) << 4) ^ ((row & 8) << 2)));
}
// LDS-visibility barrier that does NOT drain vmcnt.
__device__ __forceinline__ void ldsbar() {
  __builtin_amdgcn_sched_barrier(0);
  asm volatile("s_waitcnt lgkmcnt(0)");
  __builtin_amdgcn_s_barrier();
  __builtin_amdgcn_sched_barrier(0);
}

// ---------------- weight pack: fp32 (K,256) -> bf16 32x32x16 B-frags ----------
// packet p (64 lanes x 8): kt16 = K/16 step, nt32 = 32-col group.
// dst[p*8+i] = W[kt16*16 + (lane>>5)*8 + i][nt32*32 + (lane&31)]
__global__ void pack_weights_kernel(const float* __restrict__ W1a, const float* __restrict__ W1b,
                                    const float* __restrict__ Wa, const float* __restrict__ Wb,
                                    short* __restrict__ ws) {
  int p = blockIdx.x * blockDim.x + threadIdx.x;
  const int P1 = 10240;           // W1a: 20 kt16 * 8 nt32 * 64
  const int P2 = P1 + 8192;       // W1b: 16*8*64
  const int P3 = P2 + 8 * 18432;  // Wa: 36*8*64 per layer
  const int P4 = P3 + 8 * 8192;   // Wb
  if (p >= P4) return;
  const float* src;
  int q;
  if (p < P1)      { src = W1a; q = p; }
  else if (p < P2) { src = W1b; q = p - P1; }
  else if (p < P3) { q = p - P2; int l = q / 18432; q -= l * 18432; src = Wa + l * 147456; }
  else             { q = p - P3; int l = q / 8192;  q -= l * 8192;  src = Wb + l * 65536; }
  const int lane = q & 63, t = q >> 6, nt = t & 7, kt = t >> 3;
  const int k0 = (kt << 4) + ((lane >> 5) << 3);
  const int n  = (nt << 5) + (lane & 31);
  short* dst = ws + (size_t)p * 8;
#pragma unroll
  for (int i = 0; i < 8; ++i) dst[i] = f2bf(src[(size_t)(k0 + i) * 256 + n]);
}

// ---------------- fused MLP ----------------
// LDS (bytes): xyz [0,40960) s640 ; x [40960,73728) s512 ; t [73728,106496) s512
#define XB 40960
#define TB 73728

struct AF { bfv8 r0, r1; };
struct Pre { bfv8 b; AF a; };

__device__ __forceinline__ bfv8 bfrag(const short* __restrict__ wp, int kt16, int nt32, int lane) {
  const short* base = wp + (((size_t)((kt16 << 3) + nt32)) << 9);  // wave-uniform
  return *(const bfv8*)(base + (lane << 3));
}

// NKT/SPLIT in kt16 (K=16) units.
template<int NKT, int SPLIT, bool LEAKY, bool MIDBAR, bool PRE_A, bool PRE_NEXT_A>
__device__ __forceinline__ Pre do_gemm(short* lds,
    int a1Base, int a1S, int a2Base, int a2S,
    const short* __restrict__ wp, const short* __restrict__ wpn,
    const float* __restrict__ bias, int outBase,
    int wc, int lane, Pre pre)
{
  const int row = lane & 31;
  const int xr  = ((row & 7) << 4) ^ ((row & 8) << 2);
  const int kl  = (lane >> 5) << 4;   // 0 or 16
  const float bv = bias[(wc << 5) + row];

  f32x16 acc[2][2];
#pragma unroll
  for (int r = 0; r < 2; ++r) { acc[r][0] = (f32x16)0.f; acc[r][1] = (f32x16)0.f; }

  // 4 swizzle bases per region (kk&3 determines colbyte bits 5-6; +128 per kk>>2)
  const char* A1[4]; const char* A2[4];
#pragma unroll
  for (int m = 0; m < 4; ++m) {
    A1[m] = (const char*)lds + a1Base + row * a1S + (((m << 5) + kl) ^ xr);
    A2[m] = (const char*)lds + a2Base + row * a2S + (((m << 5) + kl) ^ xr);
  }
  auto aLoad = [&](int kt, AF& dst) {
    const bool g1 = kt < SPLIT;
    const int kk  = g1 ? kt : kt - SPLIT;
    const int st  = g1 ? a1S : a2S;
    const char* b = (g1 ? A1[kk & 3] : A2[kk & 3]) + (kk >> 2) * 128;
    dst.r0 = *(const bfv8*)(b);
    dst.r1 = *(const bfv8*)(b + (st << 5));   // +32 rows
  };

  bfv8 bst[4];
  AF ast[2];
  bst[0] = pre.b;
  if (NKT > 1) bst[1] = bfrag(wp, 1, wc, lane);
  if (NKT > 2) bst[2] = bfrag(wp, 2, wc, lane);
  if (PRE_A) ast[0] = pre.a; else aLoad(0, ast[0]);
  Pre nxt;

#pragma unroll
  for (int i = 0; i < NKT; ++i) {
    // hidden barrier: x becomes visible; loads for kt16 < SPLIT read only xyz
    if (MIDBAR && i == SPLIT - 2) ldsbar();
    if (i + 3 < NKT) {
      bst[(i + 3) & 3] = bfrag(wp, i + 3, wc, lane);
    } else if (i + 3 == NKT || (NKT <= 3 && i == 0)) {  // next gemm's first B frag
      nxt.b = bfrag(wpn, 0, wc, lane);
    }
    if (i + 1 < NKT) aLoad(i + 1, ast[(i + 1) & 1]);
    if (PRE_NEXT_A && i == NKT - 1) {  // next gemm-a's kt16=0 A (xyz, immutable)
      const char* bx = (const char*)lds + row * 640 + (kl ^ xr);
      nxt.a.r0 = *(const bfv8*)(bx);
      nxt.a.r1 = *(const bfv8*)(bx + (640 << 5));
    }
    const AF& ac = ast[i & 1];
    __builtin_amdgcn_s_setprio(1);
    acc[0][i & 1] = __builtin_amdgcn_mfma_f32_32x32x16_bf16(ac.r0, bst[i & 3], acc[0][i & 1], 0, 0, 0);
    acc[1][i & 1] = __builtin_amdgcn_mfma_f32_32x32x16_bf16(ac.r1, bst[i & 3], acc[1][i & 1], 0, 0, 0);
    __builtin_amdgcn_s_setprio(0);
  }
  // combine K-parallel pairs, bias + leaky + bf16 -> b16 stores
  const int colb = ((wc << 5) + row) << 1;
#pragma unroll
  for (int rt = 0; rt < 2; ++rt) {
    const f32x16 a = acc[rt][0] + acc[rt][1];
#pragma unroll
    for (int r = 0; r < 16; ++r) {
      float v = a[r] + bv;
      if (LEAKY) v = fmaxf(v, 0.01f * v);
      const int orow = (rt << 5) + (r & 3) + ((r >> 2) << 3) + ((lane >> 5) << 2);
      *(short*)((char*)lds + swzaddr(outBase, 512, orow, colb)) = f2bf(v);
    }
  }
  return nxt;
}

__launch_bounds__(512, 1)
__global__ void geo2vec_kernel(const float* __restrict__ xy, const int* __restrict__ idx,
    const float* __restrict__ emb,
    const float* __restrict__ b1a, const float* __restrict__ b1b,
    const float* __restrict__ ba, const float* __restrict__ bb,
    const float* __restrict__ W2, const float* __restrict__ b2,
    const short* __restrict__ wp, float* __restrict__ out)
{
  __shared__ short lds[53248];  // 104 KB
  const int tid = threadIdx.x;
  const int lane = tid & 63;
  const int wc = __builtin_amdgcn_readfirstlane(tid >> 6);  // wave = 32-col group

  Pre pre;
  pre.b = bfrag(wp, 0, wc, lane);

  // ---- prologue: pos-encode + gather z -> xyz tile (64 x 320 bf16) ----
  {
    const int g = tid >> 3, j = tid & 7;  // 8 threads per row
    const int row = blockIdx.x * 64 + g;
    const float xv = xy[2 * row], yv = xy[2 * row + 1];
    const float rv = sqrtf(xv * xv + yv * yv);
    union { short s[8]; i32x4 v; } tmp;
#pragma unroll
    for (int i = 0; i < 8; ++i) {
      const int c = 8 * j + i;
      float fv;
      if (c < 2)       fv = c ? yv : xv;
      else if (c < 22) { int m = c - 2;  float f = 1.0f + (5.0f / 9.0f) * (m >> 1); fv = sinf(((m & 1) ? yv : xv) * f); }
      else if (c < 42) { int m = c - 22; float f = 1.0f + (5.0f / 9.0f) * (m >> 1); fv = cosf(((m & 1) ? yv : xv) * f); }
      else if (c < 44) fv = (c == 42) ? xv : yv;
      else if (c < 54) fv = sinf(rv * (1.0f + (5.0f / 9.0f) * (c - 44)));
      else             fv = cosf(rv * (1.0f + (5.0f / 9.0f) * (c - 54)));
      tmp.s[i] = f2bf(fv);
    }
    *(i32x4*)((char*)lds + swzaddr(0, 640, g, j << 4)) = tmp.v;
    const float* zr = emb + (size_t)(unsigned)idx[row] * 256;
#pragma unroll
    for (int c4 = 0; c4 < 4; ++c4) {
      const int cel = j * 32 + c4 * 8;
      const float4 f0 = *(const float4*)(zr + cel);
      const float4 f1 = *(const float4*)(zr + cel + 4);
      union { short s[8]; i32x4 v; } t2;
      t2.s[0] = f2bf(f0.x); t2.s[1] = f2bf(f0.y); t2.s[2] = f2bf(f0.z); t2.s[3] = f2bf(f0.w);
      t2.s[4] = f2bf(f1.x); t2.s[5] = f2bf(f1.y); t2.s[6] = f2bf(f1.z); t2.s[7] = f2bf(f1.w);
      *(i32x4*)((char*)lds + swzaddr(0, 640, g, (64 + cel) << 1)) = t2.v;
    }
  }
  ldsbar();

  // layer 1: a (K=320, xyz) -> t ; hard bar ; b (K=256, t) -> x
  pre = do_gemm<20, 20, true,  false, false, false>(lds, 0, 640, 0, 640,
        wp, wp + 81920, b1a, TB, wc, lane, pre);
  ldsbar();
  pre = do_gemm<16, 16, false, false, false, true>(lds, TB, 512, TB, 512,
        wp + 81920, wp + 147456, b1b, XB, wc, lane, pre);
  // NO barrier here: mid-layer gemm-a carries it inside (MIDBAR)
  for (int l = 0; l < 8; ++l) {
    const short* wa = wp + 147456 + l * 147456;
    const short* wb = wp + 1327104 + l * 65536;
    const short* wan = (l < 7) ? (wa + 147456) : wp;  // dummy (valid mem) on last layer
    pre = do_gemm<36, 20, true, true, true, false>(lds, 0, 640, XB, 512,
          wa, wb, ba + l * 256, TB, wc, lane, pre);
    ldsbar();  // t ready (hard)
    pre = do_gemm<16, 16, false, false, false, true>(lds, TB, 512, TB, 512,
          wb, wan, bb + l * 256, XB, wc, lane, pre);
    // no trailing barrier: next a's MIDBAR (or the final ldsbar) covers it
  }
  ldsbar();  // x ready for the final reduce

  // final: out = x @ W2 + b2 ; 8 threads per row (32 cols each), width-8 reduce
  {
    const int r = tid >> 3, j = tid & 7;
    float sum = 0.f;
#pragma unroll
    for (int h = 0; h < 4; ++h) {
      const int cb = 64 * j + 16 * h;
      const s16x8 v = *(const s16x8*)((const char*)lds + swzaddr(XB, 512, r, cb));
      const int c0 = 32 * j + 8 * h;
      const float4 w0 = *(const float4*)(W2 + c0);
      const float4 w1 = *(const float4*)(W2 + c0 + 4);
      sum += bf2f(v[0]) * w0.x + bf2f(v[1]) * w0.y + bf2f(v[2]) * w0.z + bf2f(v[3]) * w0.w;
      sum += bf2f(v[4]) * w1.x + bf2f(v[5]) * w1.y + bf2f(v[6]) * w1.z + bf2f(v[7]) * w1.w;
    }
    sum += __shfl_xor(sum, 1); sum += __shfl_xor(sum, 2); sum += __shfl_xor(sum, 4);
    if (j == 0) out[blockIdx.x * 64 + r] = sum + b2[0];
  }
}

extern "C" void kernel_launch(void* const* d_in, const int* in_sizes, int n_in,
                              void* d_out, int out_size, void* d_ws, size_t ws_size,
                              hipStream_t stream) {
  const float* xy  = (const float*)d_in[0];
  const int*   idx = (const int*)d_in[1];
  const float* emb = (const float*)d_in[2];
  const float* W1a = (const float*)d_in[3];
  const float* b1a = (const float*)d_in[4];
  const float* W1b = (const float*)d_in[5];
  const float* b1b = (const float*)d_in[6];
  const float* Wa  = (const float*)d_in[7];
  const float* ba  = (const float*)d_in[8];
  const float* Wb  = (const float*)d_in[9];
  const float* bb  = (const float*)d_in[10];
  const float* W2  = (const float*)d_in[11];
  const float* b2  = (const float*)d_in[12];
  short* ws = (short*)d_ws;
  const int B = in_sizes[1];

  hipLaunchKernelGGL(pack_weights_kernel, dim3(904), dim3(256), 0, stream,
                     W1a, W1b, Wa, Wb, ws);
  hipLaunchKernelGGL(geo2vec_kernel, dim3(B / 64), dim3(512), 0, stream,
                     xy, idx, emb, b1a, b1b, ba, bb, W2, b2, ws, (float*)d_out);
}